// Round 13
// baseline (207.043 us; speedup 1.0000x reference)
//
#include <hip/hip_runtime.h>

typedef int intx4 __attribute__((ext_vector_type(4)));

#define GN 4096
#define GK 1024
#define BM 128
#define BN 128
#define BK 256          // K-bytes per tile row -> 4 K-iters, 8 barriers/block
#define INVT (1.0f/0.03f)
#define QS 24.0f        // int8 quant scale; dots <= 1024*127^2 < 2^24 (fp32-exact)
#define NTILES 528      // 32*33/2 upper-tri tiles per modality
#define NCROSS 1024     // 32*32 cross tiles

static __device__ __forceinline__ int q8(float x) {
    int v = __float2int_rn(x * QS);
    return v < -127 ? -127 : (v > 127 ? 127 : v);
}

// One block per index i: int8-quantize post-row i AND brand-row i, both
// inv-norms (of quantized ints) and the cross-diag int dot, single pass.
// Also zeroes the accumulators + out (replaces hipMemsetAsync dispatches).
__global__ __launch_bounds__(256)
void prep_all(const float* __restrict__ brand, const float* __restrict__ post,
              unsigned char* __restrict__ brandq, unsigned char* __restrict__ postq,
              float* __restrict__ inv_brand, float* __restrict__ inv_post,
              float* __restrict__ dvec, float* __restrict__ accs,
              float* __restrict__ out) {
    const int i = blockIdx.x, tid = threadIdx.x;
    const int wave = tid >> 6, lane = tid & 63;
    __shared__ float swp[4], swb[4], swd[4];

    float4 pv = ((const float4*)(post  + (size_t)i * GK))[tid];
    float4 bv = ((const float4*)(brand + (size_t)i * GK))[tid];
    int p0 = q8(pv.x), p1 = q8(pv.y), p2 = q8(pv.z), p3 = q8(pv.w);
    int b0 = q8(bv.x), b1 = q8(bv.y), b2 = q8(bv.z), b3 = q8(bv.w);
    ((int*)(postq  + (size_t)i * GK))[tid] =
        (p0 & 255) | ((p1 & 255) << 8) | ((p2 & 255) << 16) | ((p3 & 255) << 24);
    ((int*)(brandq + (size_t)i * GK))[tid] =
        (b0 & 255) | ((b1 & 255) << 8) | ((b2 & 255) << 16) | ((b3 & 255) << 24);

    // per-thread int partials (<= 4*127^2), accumulated as exact-int floats
    float ssp = (float)(p0 * p0 + p1 * p1 + p2 * p2 + p3 * p3);
    float ssb = (float)(b0 * b0 + b1 * b1 + b2 * b2 + b3 * b3);
    float ssd = (float)(p0 * b0 + p1 * b1 + p2 * b2 + p3 * b3);
    #pragma unroll
    for (int off = 32; off > 0; off >>= 1) {
        ssp += __shfl_down(ssp, off);
        ssb += __shfl_down(ssb, off);
        ssd += __shfl_down(ssd, off);
    }
    if (lane == 0) { swp[wave] = ssp; swb[wave] = ssb; swd[wave] = ssd; }
    __syncthreads();
    if (tid == 0) {
        inv_post[i]  = 1.0f / sqrtf(swp[0] + swp[1] + swp[2] + swp[3]);
        inv_brand[i] = 1.0f / sqrtf(swb[0] + swb[1] + swb[2] + swb[3]);
        dvec[i]      = swd[0] + swd[1] + swd[2] + swd[3];
    } else if (tid == 64) {
        accs[i] = 0.f; accs[GN + i] = 0.f; accs[2 * GN + i] = 0.f; accs[3 * GN + i] = 0.f;
        if (i == 0) out[0] = 0.f;
    }
}

// Unified GEMM dispatch, int8 16x16x64 MFMA (R11-verified shape/epilogue).
// B tile LDS-staged (128 rows x 256 B = 32 KB, 4 K-iters, 8 barriers/block);
// A fragments load DIRECTLY from global (L2/L3-hot 8 MB inputs), fully
// coalesced: one dwordx4 instr covers 16 rows x 64 B.
// B LDS rows = 256 B = 16 chunks of 16 B; chunk c of row r at slot c^(r&7)
// (conflict-free for DMA writes and b128 fragment reads).
__global__ __launch_bounds__(256, 4)
void gemm_all(const unsigned char* __restrict__ postq, const unsigned char* __restrict__ brandq,
              const float* __restrict__ dvec,
              const float* __restrict__ inv_post, const float* __restrict__ inv_brand,
              float* __restrict__ sum_post, float* __restrict__ cnt_post,
              float* __restrict__ sum_brand, float* __restrict__ cnt_brand) {
    __shared__ __align__(16) unsigned char Bs[BN * BK];   // 32 KB; epilogue red alias

    const int tid = threadIdx.x;
    const int wave = tid >> 6, lane = tid & 63;
    const int wm = (wave >> 1) * 64, wn = (wave & 1) * 64;

    int idx = blockIdx.x;
    const unsigned char *A, *B;
    const float *invA, *invB;
    float *srow, *scol, *crow, *ccol;
    int bm, bn;
    float iaScale;
    bool is_cross, do_cols;

    if (idx < NCROSS) {
        is_cross = true; do_cols = true;
        bm = (idx >> 5) * BM; bn = (idx & 31) * BN;
        A = postq; B = brandq;
        invA = inv_post; invB = inv_brand; iaScale = INVT;
        srow = sum_post; crow = cnt_post; scol = sum_brand; ccol = cnt_brand;
    } else {
        is_cross = false;
        idx -= NCROSS;
        const unsigned char* X; const float* invx; float* sacc;
        if (idx >= NTILES) { idx -= NTILES; X = brandq; invx = inv_brand; sacc = sum_brand; }
        else               {               X = postq;  invx = inv_post;  sacc = sum_post;  }
        int J = (int)((sqrtf(8.f * idx + 1.f) - 1.f) * 0.5f);
        while ((J + 1) * (J + 2) / 2 <= idx) ++J;
        while (J * (J + 1) / 2 > idx) --J;
        const int I = idx - J * (J + 1) / 2;
        bm = I * BM; bn = J * BN;
        A = X; B = X;
        invA = invx; invB = invx; iaScale = 0.8f * INVT;
        srow = sacc; scol = sacc; crow = nullptr; ccol = nullptr;
        do_cols = (I != J);
    }

    const int lrow = lane & 15;
    const int kq = lane >> 4;                 // 0..3

    // B DMA: instr s stages 4 rows (r0 = wave*32 + s*4); lane l -> row r0+(l>>4),
    // LDS slot l&15, global chunk (l&15)^(((s&1)*4)|(l>>4)).
    const int dr = lane >> 4;                 // row within 4-row strip
    const int dslot = lane & 15;
    // A fragment base: lane (lrow,kq) reads row bm+wm+t*16+lrow, bytes [h*64+kq*16,+16)
    const unsigned char* aBase = A + (size_t)(bm + wm + lrow) * GK + kq * 16;

    intx4 acc[4][4] = {};
    #pragma unroll 1
    for (int k0 = 0; k0 < GK; k0 += BK) {
        #pragma unroll
        for (int s = 0; s < 8; ++s) {
            const int r0 = wave * 32 + s * 4;
            const int key = ((s & 1) * 4) | dr;
            __builtin_amdgcn_global_load_lds(
                (const __attribute__((address_space(1))) void*)
                    (B + (size_t)(bn + r0 + dr) * GK + k0 + ((dslot ^ key) * 16)),
                (__attribute__((address_space(3))) void*)(Bs + r0 * BK), 16, 0, 0);
        }
        __syncthreads();

        #pragma unroll
        for (int h = 0; h < 4; ++h) {         // 64-B k-step within the 256-B tile
            intx4 bfr[4];
            #pragma unroll
            for (int u = 0; u < 4; ++u) {
                const int m = wn + u * 16 + lrow;
                bfr[u] = *(const intx4*)(Bs + m * BK + (((4 * h + kq) ^ (m & 7)) * 16));
            }
            #pragma unroll
            for (int t = 0; t < 4; ++t) {
                const intx4 af = *(const intx4*)(aBase + (size_t)t * (16 * GK) + k0 + h * 64);
                #pragma unroll
                for (int u = 0; u < 4; ++u)
                    acc[t][u] = __builtin_amdgcn_mfma_i32_16x16x64_i8(
                        af, bfr[u], acc[t][u], 0, 0, 0);
            }
        }
        __syncthreads();   // also separates last tile reads from epilogue red alias
    }

    // ---- epilogue (C/D: col=lane&15, row=(lane>>4)*4+reg; R11-verified) ----
    const int cn = lane & 15, rq = lane >> 4;
    float ib_c[4], db_c[4];
    #pragma unroll
    for (int u = 0; u < 4; ++u) {
        const int gc = bn + wn + u * 16 + cn;
        ib_c[u] = invB[gc];
        db_c[u] = is_cross ? dvec[gc] : 0.f;
    }

    float csum[4] = {}, ccnt[4] = {};
    float my_rs = 0.f, my_rc = 0.f;
    #pragma unroll
    for (int t = 0; t < 4; ++t) {
        #pragma unroll
        for (int r = 0; r < 4; ++r) {
            const int rl = wm + t * 16 + rq * 4 + r;
            const int grow = bm + rl;
            const float ia = invA[grow] * iaScale;
            float v = 0.f, w = 0.f;
            if (is_cross) {
                const float da = dvec[grow];
                #pragma unroll
                for (int u = 0; u < 4; ++u) {
                    const float s = (float)acc[t][u][r];   // exact int < 2^24
                    const int gcol = bn + wn + u * 16 + cn;
                    const bool diag = (grow == gcol);
                    float e = __expf(s * ia * ib_c[u]);
                    v += e;
                    csum[u] += e;
                    w += (!diag && s > da) ? 1.f : 0.f;
                    ccnt[u] += (!diag && s > db_c[u]) ? 1.f : 0.f;
                }
                w += __shfl_xor(w, 1); w += __shfl_xor(w, 2);
                w += __shfl_xor(w, 4); w += __shfl_xor(w, 8);
            } else {
                #pragma unroll
                for (int u = 0; u < 4; ++u) {
                    const float s = (float)acc[t][u][r];
                    const int gcol = bn + wn + u * 16 + cn;
                    float e = (grow == gcol) ? 1.0f : __expf(s * ia * ib_c[u]);
                    v += e;
                    csum[u] += e;
                }
            }
            v += __shfl_xor(v, 1); v += __shfl_xor(v, 2);
            v += __shfl_xor(v, 4); v += __shfl_xor(v, 8);
            if (cn == ((t << 2) | r)) { my_rs = v; my_rc = w; }
        }
    }

    // reduction scratch aliases the (dead) tile LDS
    float (*redRS)[2] = (float(*)[2])(Bs);
    float (*redRC)[2] = (float(*)[2])(Bs + 1024);
    float (*redCS)[2] = (float(*)[2])(Bs + 2048);
    float (*redCC)[2] = (float(*)[2])(Bs + 3072);

    const int rl_local = wm + (cn >> 2) * 16 + rq * 4 + (cn & 3);
    redRS[rl_local][wave & 1] = my_rs;
    redRC[rl_local][wave & 1] = my_rc;

    float my_cs = 0.f, my_cc = 0.f;
    #pragma unroll
    for (int u = 0; u < 4; ++u) {
        float v = csum[u];
        v += __shfl_xor(v, 16); v += __shfl_xor(v, 32);
        if (rq == u) my_cs = v;
        if (is_cross) {
            float w = ccnt[u];
            w += __shfl_xor(w, 16); w += __shfl_xor(w, 32);
            if (rq == u) my_cc = w;
        }
    }
    const int cl_local = wn + rq * 16 + cn;
    redCS[cl_local][wave >> 1] = my_cs;
    redCC[cl_local][wave >> 1] = my_cc;
    __syncthreads();

    if (tid < 128) {
        atomicAdd(&srow[bm + tid], redRS[tid][0] + redRS[tid][1]);
        if (is_cross) atomicAdd(&crow[bm + tid], redRC[tid][0] + redRC[tid][1]);
    } else if (do_cols) {
        const int t2 = tid - 128;
        atomicAdd(&scol[bn + t2], redCS[t2][0] + redCS[t2][1]);
        if (is_cross) atomicAdd(&ccol[bn + t2], redCC[t2][0] + redCC[t2][1]);
    }
}

// Final per-row loss assembly + global sum
__global__ __launch_bounds__(256)
void final_loss(const float* __restrict__ sum_post, const float* __restrict__ cnt_post,
                const float* __restrict__ sum_brand, const float* __restrict__ cnt_brand,
                const float* __restrict__ dvec,
                const float* __restrict__ inv_post, const float* __restrict__ inv_brand,
                float* __restrict__ out) {
    const int i = blockIdx.x * 256 + threadIdx.x;
    float dl = dvec[i] * inv_post[i] * inv_brand[i] * INVT;
    float lp = logf(sum_post[i]);
    float lb = logf(sum_brand[i]);
    float rp = 1.0f / (4096.0f - cnt_post[i]) + 1.0f;
    float rb = 1.0f / (4096.0f - cnt_brand[i]) + 1.0f;
    float loss = 0.5f * (rb * (lb - dl) + rp * (lp - dl));
    #pragma unroll
    for (int off = 32; off > 0; off >>= 1) loss += __shfl_down(loss, off);
    __shared__ float sw[4];
    int wave = threadIdx.x >> 6, lane = threadIdx.x & 63;
    if (lane == 0) sw[wave] = loss;
    __syncthreads();
    if (threadIdx.x == 0) atomicAdd(out, sw[0] + sw[1] + sw[2] + sw[3]);
}

extern "C" void kernel_launch(void* const* d_in, const int* in_sizes, int n_in,
                              void* d_out, int out_size, void* d_ws, size_t ws_size,
                              hipStream_t stream) {
    const float* brand = (const float*)d_in[0];
    const float* post  = (const float*)d_in[1];
    float* out = (float*)d_out;

    char* ws = (char*)d_ws;
    unsigned char* postq  = (unsigned char*)ws;                          // 4 MB
    unsigned char* brandq = postq + (size_t)GN * GK;                     // 4 MB
    float* inv_post  = (float*)(brandq + (size_t)GN * GK);
    float* inv_brand = inv_post + GN;
    float* dvec      = inv_brand + GN;
    float* accs      = dvec + GN;        // [sum_post, sum_brand, cnt_post, cnt_brand]
    float* sum_post  = accs;
    float* sum_brand = accs + GN;
    float* cnt_post  = accs + 2 * GN;
    float* cnt_brand = accs + 3 * GN;

    prep_all<<<GN, 256, 0, stream>>>(brand, post, brandq, postq,
                                     inv_brand, inv_post, dvec, accs, out);
    gemm_all<<<NCROSS + 2 * NTILES, 256, 0, stream>>>(postq, brandq, dvec,
                                                      inv_post, inv_brand,
                                                      sum_post, cnt_post,
                                                      sum_brand, cnt_brand);
    final_loss<<<GN / 256, 256, 0, stream>>>(sum_post, cnt_post, sum_brand, cnt_brand,
                                             dvec, inv_post, inv_brand, out);
}

// Round 14
// 144.249 us; speedup vs baseline: 1.4353x; 1.4353x over previous
//
#include <hip/hip_runtime.h>

typedef int intx4 __attribute__((ext_vector_type(4)));

#define GN 4096
#define GK 1024
#define BM 128
#define BN 128
#define INVT (1.0f/0.03f)
#define QS 24.0f        // int8 quant scale; dots <= 1024*127^2 < 2^24 (fp32-exact)
#define NTILES 528      // 32*33/2 upper-tri tiles per modality
#define NCROSS 1024     // 32*32 cross tiles

static __device__ __forceinline__ int q8(float x) {
    int v = __float2int_rn(x * QS);
    return v < -127 ? -127 : (v > 127 ? 127 : v);
}

// One block per index i: int8-quantize post-row i AND brand-row i, both
// inv-norms (of quantized ints) and the cross-diag int dot, single pass.
// Also zeroes the accumulators + out (replaces hipMemsetAsync dispatches).
__global__ __launch_bounds__(256)
void prep_all(const float* __restrict__ brand, const float* __restrict__ post,
              unsigned char* __restrict__ brandq, unsigned char* __restrict__ postq,
              float* __restrict__ inv_brand, float* __restrict__ inv_post,
              float* __restrict__ dvec, float* __restrict__ accs,
              float* __restrict__ out) {
    const int i = blockIdx.x, tid = threadIdx.x;
    const int wave = tid >> 6, lane = tid & 63;
    __shared__ float swp[4], swb[4], swd[4];

    float4 pv = ((const float4*)(post  + (size_t)i * GK))[tid];
    float4 bv = ((const float4*)(brand + (size_t)i * GK))[tid];
    int p0 = q8(pv.x), p1 = q8(pv.y), p2 = q8(pv.z), p3 = q8(pv.w);
    int b0 = q8(bv.x), b1 = q8(bv.y), b2 = q8(bv.z), b3 = q8(bv.w);
    ((int*)(postq  + (size_t)i * GK))[tid] =
        (p0 & 255) | ((p1 & 255) << 8) | ((p2 & 255) << 16) | ((p3 & 255) << 24);
    ((int*)(brandq + (size_t)i * GK))[tid] =
        (b0 & 255) | ((b1 & 255) << 8) | ((b2 & 255) << 16) | ((b3 & 255) << 24);

    // per-thread int partials (<= 4*127^2), accumulated as exact-int floats
    float ssp = (float)(p0 * p0 + p1 * p1 + p2 * p2 + p3 * p3);
    float ssb = (float)(b0 * b0 + b1 * b1 + b2 * b2 + b3 * b3);
    float ssd = (float)(p0 * b0 + p1 * b1 + p2 * b2 + p3 * b3);
    #pragma unroll
    for (int off = 32; off > 0; off >>= 1) {
        ssp += __shfl_down(ssp, off);
        ssb += __shfl_down(ssb, off);
        ssd += __shfl_down(ssd, off);
    }
    if (lane == 0) { swp[wave] = ssp; swb[wave] = ssb; swd[wave] = ssd; }
    __syncthreads();
    if (tid == 0) {
        inv_post[i]  = 1.0f / sqrtf(swp[0] + swp[1] + swp[2] + swp[3]);
        inv_brand[i] = 1.0f / sqrtf(swb[0] + swb[1] + swb[2] + swb[3]);
        dvec[i]      = swd[0] + swd[1] + swd[2] + swd[3];
    } else if (tid == 64) {
        accs[i] = 0.f; accs[GN + i] = 0.f; accs[2 * GN + i] = 0.f; accs[3 * GN + i] = 0.f;
        if (i == 0) out[0] = 0.f;
    }
}

// Unified GEMM dispatch, int8 16x16x64 MFMA (R11-verified shape/epilogue).
// Double-buffered BK=64 staging: 4 x 8 KB buffers (32 KB total, 5 blocks/CU).
// K-loop: barrier -> issue DMA(k+1 -> other buf) -> consume(k). The vmcnt(0)
// drain at the next barrier lands AFTER a full MFMA phase -> latency hidden.
// LDS rows = 64 B = 4 chunks of 16 B; chunk c of row r at slot c^((r>>1)&3)
// (conflict-free for DMA writes and b128 fragment reads; R6/R8-verified).
__global__ __launch_bounds__(256, 5)
void gemm_all(const unsigned char* __restrict__ postq, const unsigned char* __restrict__ brandq,
              const float* __restrict__ dvec,
              const float* __restrict__ inv_post, const float* __restrict__ inv_brand,
              float* __restrict__ sum_post, float* __restrict__ cnt_post,
              float* __restrict__ sum_brand, float* __restrict__ cnt_brand) {
    __shared__ __align__(16) unsigned char smem[32768];   // As0|As1|Bs0|Bs1; red alias
    unsigned char* const As0 = smem;
    unsigned char* const As1 = smem + 8192;
    unsigned char* const Bs0 = smem + 16384;
    unsigned char* const Bs1 = smem + 24576;

    const int tid = threadIdx.x;
    const int wave = tid >> 6, lane = tid & 63;
    const int wm = (wave >> 1) * 64, wn = (wave & 1) * 64;

    int idx = blockIdx.x;
    const unsigned char *A, *B;
    const float *invA, *invB;
    float *srow, *scol, *crow, *ccol;
    int bm, bn;
    float iaScale;
    bool is_cross, do_cols;

    if (idx < NCROSS) {
        is_cross = true; do_cols = true;
        bm = (idx >> 5) * BM; bn = (idx & 31) * BN;
        A = postq; B = brandq;
        invA = inv_post; invB = inv_brand; iaScale = INVT;
        srow = sum_post; crow = cnt_post; scol = sum_brand; ccol = cnt_brand;
    } else {
        is_cross = false;
        idx -= NCROSS;
        const unsigned char* X; const float* invx; float* sacc;
        if (idx >= NTILES) { idx -= NTILES; X = brandq; invx = inv_brand; sacc = sum_brand; }
        else               {               X = postq;  invx = inv_post;  sacc = sum_post;  }
        int J = (int)((sqrtf(8.f * idx + 1.f) - 1.f) * 0.5f);
        while ((J + 1) * (J + 2) / 2 <= idx) ++J;
        while (J * (J + 1) / 2 > idx) --J;
        const int I = idx - J * (J + 1) / 2;
        bm = I * BM; bn = J * BN;
        A = X; B = X;
        invA = invx; invB = invx; iaScale = 0.8f * INVT;
        srow = sacc; scol = sacc; crow = nullptr; ccol = nullptr;
        do_cols = (I != J);
    }

    const int lrow = lane & 15;
    const int kq = lane >> 4;                 // 0..3
    const int swzkey = (lane >> 1) & 3;       // = ((row)>>1)&3 for row = base16+lrow

    // DMA: lane l -> strip row l>>2 (16 rows/instr), LDS slot l&3,
    // global chunk (l&3)^((l>>3)&3)  [key = (row>>1)&3].
    const size_t dma_off = (size_t)(lane >> 2) * GK + ((((lane & 3) ^ ((lane >> 3) & 3))) * 16);
    const unsigned char* aSrc = A + (size_t)(bm + wave * 32) * GK + dma_off;
    const unsigned char* bSrc = B + (size_t)(bn + wave * 32) * GK + dma_off;
    const int ldsOff = (wave * 32) * 64;      // per-wave 32-row strip

#define STAGE(k0, Asb, Bsb)                                                             \
    {                                                                                   \
        _Pragma("unroll")                                                               \
        for (int s = 0; s < 2; ++s) {                                                   \
            __builtin_amdgcn_global_load_lds(                                           \
                (const __attribute__((address_space(1))) void*)                         \
                    (aSrc + (size_t)s * 16 * GK + (k0)),                                \
                (__attribute__((address_space(3))) void*)((Asb) + ldsOff + s * 1024),   \
                16, 0, 0);                                                              \
            __builtin_amdgcn_global_load_lds(                                           \
                (const __attribute__((address_space(1))) void*)                         \
                    (bSrc + (size_t)s * 16 * GK + (k0)),                                \
                (__attribute__((address_space(3))) void*)((Bsb) + ldsOff + s * 1024),   \
                16, 0, 0);                                                              \
        }                                                                               \
    }

#define CONSUME(Asb, Bsb)                                                               \
    {                                                                                   \
        intx4 bfr[4];                                                                   \
        _Pragma("unroll")                                                               \
        for (int u = 0; u < 4; ++u)                                                     \
            bfr[u] = *(const intx4*)((Bsb) + (wn + u * 16 + lrow) * 64 +                \
                                     ((kq ^ swzkey) * 16));                             \
        _Pragma("unroll")                                                               \
        for (int t = 0; t < 4; ++t) {                                                   \
            const intx4 af = *(const intx4*)((Asb) + (wm + t * 16 + lrow) * 64 +        \
                                             ((kq ^ swzkey) * 16));                     \
            _Pragma("unroll")                                                           \
            for (int u = 0; u < 4; ++u)                                                 \
                acc[t][u] = __builtin_amdgcn_mfma_i32_16x16x64_i8(                      \
                    af, bfr[u], acc[t][u], 0, 0, 0);                                    \
        }                                                                               \
    }

    intx4 acc[4][4] = {};
    STAGE(0, As0, Bs0)
    #pragma unroll 1
    for (int kk = 0; kk < GK; kk += 128) {
        __syncthreads();                       // drain buf0 stage (hidden for kk>0)
        STAGE(kk + 64, As1, Bs1)
        CONSUME(As0, Bs0)
        __syncthreads();                       // drain buf1 stage (hidden)
        if (kk + 128 < GK) STAGE(kk + 128, As0, Bs0)
        CONSUME(As1, Bs1)
    }

    // ---- epilogue (C/D: col=lane&15, row=(lane>>4)*4+reg; R11-verified) ----
    const int cn = lane & 15, rq = lane >> 4;
    float ib_c[4], db_c[4];
    #pragma unroll
    for (int u = 0; u < 4; ++u) {
        const int gc = bn + wn + u * 16 + cn;
        ib_c[u] = invB[gc];
        db_c[u] = is_cross ? dvec[gc] : 0.f;
    }

    float csum[4] = {}, ccnt[4] = {};
    float my_rs = 0.f, my_rc = 0.f;
    #pragma unroll
    for (int t = 0; t < 4; ++t) {
        #pragma unroll
        for (int r = 0; r < 4; ++r) {
            const int rl = wm + t * 16 + rq * 4 + r;
            const int grow = bm + rl;
            const float ia = invA[grow] * iaScale;
            float v = 0.f, w = 0.f;
            if (is_cross) {
                const float da = dvec[grow];
                #pragma unroll
                for (int u = 0; u < 4; ++u) {
                    const float s = (float)acc[t][u][r];   // exact int < 2^24
                    const int gcol = bn + wn + u * 16 + cn;
                    const bool diag = (grow == gcol);
                    float e = __expf(s * ia * ib_c[u]);
                    v += e;
                    csum[u] += e;
                    w += (!diag && s > da) ? 1.f : 0.f;
                    ccnt[u] += (!diag && s > db_c[u]) ? 1.f : 0.f;
                }
                w += __shfl_xor(w, 1); w += __shfl_xor(w, 2);
                w += __shfl_xor(w, 4); w += __shfl_xor(w, 8);
            } else {
                #pragma unroll
                for (int u = 0; u < 4; ++u) {
                    const float s = (float)acc[t][u][r];
                    const int gcol = bn + wn + u * 16 + cn;
                    float e = (grow == gcol) ? 1.0f : __expf(s * ia * ib_c[u]);
                    v += e;
                    csum[u] += e;
                }
            }
            v += __shfl_xor(v, 1); v += __shfl_xor(v, 2);
            v += __shfl_xor(v, 4); v += __shfl_xor(v, 8);
            if (cn == ((t << 2) | r)) { my_rs = v; my_rc = w; }
        }
    }

    // reduction scratch aliases As0 (last read two barriers ago -> safe)
    float (*redRS)[2] = (float(*)[2])(smem);
    float (*redRC)[2] = (float(*)[2])(smem + 1024);
    float (*redCS)[2] = (float(*)[2])(smem + 2048);
    float (*redCC)[2] = (float(*)[2])(smem + 3072);

    const int rl_local = wm + (cn >> 2) * 16 + rq * 4 + (cn & 3);
    redRS[rl_local][wave & 1] = my_rs;
    redRC[rl_local][wave & 1] = my_rc;

    float my_cs = 0.f, my_cc = 0.f;
    #pragma unroll
    for (int u = 0; u < 4; ++u) {
        float v = csum[u];
        v += __shfl_xor(v, 16); v += __shfl_xor(v, 32);
        if (rq == u) my_cs = v;
        if (is_cross) {
            float w = ccnt[u];
            w += __shfl_xor(w, 16); w += __shfl_xor(w, 32);
            if (rq == u) my_cc = w;
        }
    }
    const int cl_local = wn + rq * 16 + cn;
    redCS[cl_local][wave >> 1] = my_cs;
    redCC[cl_local][wave >> 1] = my_cc;
    __syncthreads();

    if (tid < 128) {
        atomicAdd(&srow[bm + tid], redRS[tid][0] + redRS[tid][1]);
        if (is_cross) atomicAdd(&crow[bm + tid], redRC[tid][0] + redRC[tid][1]);
    } else if (do_cols) {
        const int t2 = tid - 128;
        atomicAdd(&scol[bn + t2], redCS[t2][0] + redCS[t2][1]);
        if (is_cross) atomicAdd(&ccol[bn + t2], redCC[t2][0] + redCC[t2][1]);
    }
#undef STAGE
#undef CONSUME
}

// Final per-row loss assembly + global sum
__global__ __launch_bounds__(256)
void final_loss(const float* __restrict__ sum_post, const float* __restrict__ cnt_post,
                const float* __restrict__ sum_brand, const float* __restrict__ cnt_brand,
                const float* __restrict__ dvec,
                const float* __restrict__ inv_post, const float* __restrict__ inv_brand,
                float* __restrict__ out) {
    const int i = blockIdx.x * 256 + threadIdx.x;
    float dl = dvec[i] * inv_post[i] * inv_brand[i] * INVT;
    float lp = logf(sum_post[i]);
    float lb = logf(sum_brand[i]);
    float rp = 1.0f / (4096.0f - cnt_post[i]) + 1.0f;
    float rb = 1.0f / (4096.0f - cnt_brand[i]) + 1.0f;
    float loss = 0.5f * (rb * (lb - dl) + rp * (lp - dl));
    #pragma unroll
    for (int off = 32; off > 0; off >>= 1) loss += __shfl_down(loss, off);
    __shared__ float sw[4];
    int wave = threadIdx.x >> 6, lane = threadIdx.x & 63;
    if (lane == 0) sw[wave] = loss;
    __syncthreads();
    if (threadIdx.x == 0) atomicAdd(out, sw[0] + sw[1] + sw[2] + sw[3]);
}

extern "C" void kernel_launch(void* const* d_in, const int* in_sizes, int n_in,
                              void* d_out, int out_size, void* d_ws, size_t ws_size,
                              hipStream_t stream) {
    const float* brand = (const float*)d_in[0];
    const float* post  = (const float*)d_in[1];
    float* out = (float*)d_out;

    char* ws = (char*)d_ws;
    unsigned char* postq  = (unsigned char*)ws;                          // 4 MB
    unsigned char* brandq = postq + (size_t)GN * GK;                     // 4 MB
    float* inv_post  = (float*)(brandq + (size_t)GN * GK);
    float* inv_brand = inv_post + GN;
    float* dvec      = inv_brand + GN;
    float* accs      = dvec + GN;        // [sum_post, sum_brand, cnt_post, cnt_brand]
    float* sum_post  = accs;
    float* sum_brand = accs + GN;
    float* cnt_post  = accs + 2 * GN;
    float* cnt_brand = accs + 3 * GN;

    prep_all<<<GN, 256, 0, stream>>>(brand, post, brandq, postq,
                                     inv_brand, inv_post, dvec, accs, out);
    gemm_all<<<NCROSS + 2 * NTILES, 256, 0, stream>>>(postq, brandq, dvec,
                                                      inv_post, inv_brand,
                                                      sum_post, cnt_post,
                                                      sum_brand, cnt_brand);
    final_loss<<<GN / 256, 256, 0, stream>>>(sum_post, cnt_post, sum_brand, cnt_brand,
                                             dvec, inv_post, inv_brand, out);
}